// Round 5
// baseline (55.534 us; speedup 1.0000x reference)
//
#include <hip/hip_runtime.h>

#define HEIGHT 8
#define NXCD 8

// ---------------- Kernel A: per-box params + width output ----------------
// params[2m]   = {cx, cy, s, width}
// params[2m+1] = {ca, sa, ceil(width), image_index_as_float_bits}
__global__ void __launch_bounds__(256)
box_params_kernel(const float* __restrict__ boxes,
                  const int* __restrict__ box_indices,
                  float4* __restrict__ params,
                  float* __restrict__ width_out,
                  int M, int mw)
{
    int m = blockIdx.x * blockDim.x + threadIdx.x;
    if (m >= M) return;
    const float x1  = boxes[m * 5 + 0];
    const float y1  = boxes[m * 5 + 1];
    const float x2  = boxes[m * 5 + 2];
    const float y2  = boxes[m * 5 + 3];
    const float ang = boxes[m * 5 + 4];
    const float bwd = x2 - x1, bhd = y2 - y1;
    const float width = (float)HEIGHT * bwd / bhd;   // same assoc as reference
    params[2 * m]     = make_float4((x1 + x2) * 0.5f, (y1 + y2) * 0.5f,
                                    bhd / (float)HEIGHT, width);
    params[2 * m + 1] = make_float4(cosf(ang), sinf(ang), ceilf(width),
                                    __int_as_float(box_indices[m]));
    width_out[m] = (float)mw - width;
}

// ---------------- Kernel B: bucket boxes by image&7 (one block) ----------------
__global__ void __launch_bounds__(1024)
bucket_kernel(const int* __restrict__ box_indices,
              int* __restrict__ perm,
              int* __restrict__ off_g,   // 9 entries
              int M)
{
    __shared__ int h[NXCD];
    __shared__ int base[NXCD];
    const int t    = threadIdx.x;
    const int lane = t & 63;
    if (t < NXCD) h[t] = 0;
    __syncthreads();

    // pass 1: wave-aggregated histogram
    for (int m = t; m < M; m += blockDim.x) {
        const int g = box_indices[m] & (NXCD - 1);
        #pragma unroll
        for (int q = 0; q < NXCD; ++q) {
            const unsigned long long mask = __ballot(g == q);
            if (g == q) {
                const int leader = __ffsll((unsigned long long)mask) - 1;
                if (lane == leader) atomicAdd(&h[q], __popcll(mask));
            }
        }
    }
    __syncthreads();

    if (t == 0) {
        int acc = 0;
        #pragma unroll
        for (int q = 0; q < NXCD; ++q) { base[q] = acc; off_g[q] = acc; acc += h[q]; }
        off_g[NXCD] = acc;
    }
    __syncthreads();

    // pass 2: wave-aggregated scatter (order within bucket irrelevant)
    for (int m = t; m < M; m += blockDim.x) {
        const int g = box_indices[m] & (NXCD - 1);
        #pragma unroll
        for (int q = 0; q < NXCD; ++q) {
            const unsigned long long mask = __ballot(g == q);
            if (g == q) {
                const unsigned long long lt = (1ull << lane) - 1ull;
                const int rank   = __popcll(mask & lt);
                const int leader = __ffsll((unsigned long long)mask) - 1;
                int wb = 0;
                if (lane == leader) wb = atomicAdd(&base[q], __popcll(mask));
                wb = __shfl(wb, leader, 64);
                perm[wb + rank] = m;
            }
        }
    }
}

// ---------------- Kernel C: main sampler ----------------
// 1024 blocks x 512. Block bid serves bucket (bid & 7); with round-robin
// block->XCD dispatch each XCD touches only images with idx%8==bucket
// (~2 images = ~6 MB -> L2-resident, no cross-XCD refetch).
__global__ void __launch_bounds__(512)
roi_main_kernel(const float* __restrict__ images,
                const float4* __restrict__ params,
                const int* __restrict__ perm,
                const int* __restrict__ off_g,
                float* __restrict__ crops,
                int mw, int Himg, int Wimg)
{
    const int x   = blockIdx.x & (NXCD - 1);
    const int r   = blockIdx.x >> 3;
    const int nb  = (int)gridDim.x >> 3;      // blocks per bucket
    const int tid = threadIdx.x;
    const int pbeg = off_g[x];
    const int pend = off_g[x + 1];
    const int nsamp = HEIGHT * mw;

    for (int p = pbeg + r; p < pend; p += nb) {
        const int m = perm[p];
        const float4 pA = params[2 * m];       // cx, cy, s, width
        const float4 pB = params[2 * m + 1];   // ca, sa, wlim, img-bits
        const float cx = pA.x, cy = pA.y, s = pA.z, width = pA.w;
        const float ca = pB.x, sa = pB.y, wlim = pB.z;
        const int   b  = __float_as_int(pB.w);
        const float* img = images + (size_t)b * Himg * Wimg * 3;
        float* oblk = crops + (size_t)m * nsamp * 3;

        for (int idx = tid; idx < nsamp; idx += blockDim.x) {
            int i, j;
            if (mw == 64) { i = idx >> 6; j = idx & 63; }
            else          { i = idx / mw; j = idx - i * mw; }

            const float dx = s * ((float)j - (width - 1.0f) * 0.5f);
            const float dy = s * ((float)i - ((float)HEIGHT - 1.0f) * 0.5f);
            const float sx = cx + ca * dx - sa * dy;
            const float sy = cy + sa * dx + ca * dy;

            float v0 = 0.0f, v1 = 0.0f, v2 = 0.0f;
            const bool valid = ((float)j < wlim) &&
                               (sx >= 0.0f) && (sx <= (float)(Wimg - 1)) &&
                               (sy >= 0.0f) && (sy <= (float)(Himg - 1));
            if (valid) {
                const float x0 = floorf(sx);
                const float y0 = floorf(sy);
                const int x0i = (int)x0;
                const int y0i = (int)y0;
                const int xb  = min(x0i, Wimg - 2);
                const int yb  = min(y0i, Himg - 2);
                // clamped => fractional weight collapses; keeps indices static
                const float fx = (x0i == xb) ? (sx - x0) : 1.0f;
                const float fy = (y0i == yb) ? (sy - y0) : 1.0f;

                const float* r0 = img + ((size_t)yb * Wimg + xb) * 3;
                const float* r1 = r0 + (size_t)Wimg * 3;
                float s0[6], s1[6];
                __builtin_memcpy(s0, r0, 24);
                __builtin_memcpy(s1, r1, 24);

                const float w00 = (1.0f - fx) * (1.0f - fy);
                const float w01 = fx * (1.0f - fy);
                const float w10 = (1.0f - fx) * fy;
                const float w11 = fx * fy;

                v0 = s0[0] * w00 + s0[3] * w01 + s1[0] * w10 + s1[3] * w11;
                v1 = s0[1] * w00 + s0[4] * w01 + s1[1] * w10 + s1[4] * w11;
                v2 = s0[2] * w00 + s0[5] * w01 + s1[2] * w10 + s1[5] * w11;
            }
            float* o = oblk + (size_t)idx * 3;
            o[0] = v0; o[1] = v1; o[2] = v2;
        }
    }
}

extern "C" void kernel_launch(void* const* d_in, const int* in_sizes, int n_in,
                              void* d_out, int out_size, void* d_ws, size_t ws_size,
                              hipStream_t stream) {
    const float* images      = (const float*)d_in[0];
    const float* boxes       = (const float*)d_in[2];
    const int*   box_indices = (const int*)d_in[3];

    const int M  = in_sizes[3];                       // 8192 boxes
    const int mw = (out_size - M) / (M * HEIGHT * 3); // max_width (=64)
    const int Himg = 512, Wimg = 512;

    float* crops     = (float*)d_out;
    float* width_out = crops + (size_t)M * HEIGHT * mw * 3;

    // workspace layout
    float4* params = (float4*)d_ws;                       // 2*M float4
    int*    perm   = (int*)((char*)d_ws + (size_t)2 * M * sizeof(float4));
    int*    off_g  = perm + M;                            // 9 ints

    box_params_kernel<<<(M + 255) / 256, 256, 0, stream>>>(
        boxes, box_indices, params, width_out, M, mw);
    bucket_kernel<<<1, 1024, 0, stream>>>(box_indices, perm, off_g, M);
    roi_main_kernel<<<1024, 512, 0, stream>>>(
        images, params, perm, off_g, crops, mw, Himg, Wimg);
}

// Round 6
// 41.864 us; speedup vs baseline: 1.3266x; 1.3266x over previous
//
#include <hip/hip_runtime.h>

#define HEIGHT 8
#define NXCD 8

// ---------------- prep: per-box params + width output + bucket scatter ----------------
// params[2m]   = {cx, cy, s, (width-1)/2}
// params[2m+1] = {ca, sa, ceil(width), image_index_bits}
// perm[g*M + rank] = m  for boxes with image&7 == g; cnt[g] = bucket size.
__global__ void __launch_bounds__(256)
prep_kernel(const float* __restrict__ boxes,
            const int* __restrict__ box_indices,
            float4* __restrict__ params,
            int* __restrict__ perm,
            int* __restrict__ cnt,
            float* __restrict__ width_out,
            int M, int mw)
{
    const int m    = blockIdx.x * 256 + threadIdx.x;
    const int lane = threadIdx.x & 63;
    int g = -1;
    if (m < M) {
        const float x1  = boxes[m * 5 + 0];
        const float y1  = boxes[m * 5 + 1];
        const float x2  = boxes[m * 5 + 2];
        const float y2  = boxes[m * 5 + 3];
        const float ang = boxes[m * 5 + 4];
        const float bwd = x2 - x1, bhd = y2 - y1;
        const float width = (float)HEIGHT * bwd / bhd;  // same assoc as reference
        const int   b     = box_indices[m];
        params[2 * m]     = make_float4((x1 + x2) * 0.5f, (y1 + y2) * 0.5f,
                                        bhd / (float)HEIGHT, (width - 1.0f) * 0.5f);
        params[2 * m + 1] = make_float4(cosf(ang), sinf(ang), ceilf(width),
                                        __int_as_float(b));
        width_out[m] = (float)mw - width;
        g = b & (NXCD - 1);
    }
    #pragma unroll
    for (int q = 0; q < NXCD; ++q) {
        const unsigned long long mask = __ballot(g == q);
        if (g == q) {
            const unsigned long long lt = (1ull << lane) - 1ull;
            const int rank   = __popcll(mask & lt);
            const int leader = __ffsll((unsigned long long)mask) - 1;
            int wb = 0;
            if (lane == leader) wb = atomicAdd(&cnt[q], __popcll(mask));
            wb = __shfl(wb, leader, 64);
            perm[q * M + wb + rank] = m;
        }
    }
}

// ---------------- main sampler: deep per-wave memory pipeline ----------------
struct Gth {
    float q0[6], q1[6];   // sample u=0: rows yb, yb+1 (2 px x 3 ch each)
    float q2[6], q3[6];   // sample u=1
    float fx0, fy0, fx1, fy1;
    bool  v0, v1;
};

__device__ __forceinline__ void issue_samp(
    const float* __restrict__ img, int idx, int mw, int Wimg, int Himg,
    float cx, float cy, float s, float px, float ca, float sa, float wlim,
    float qa[6], float qb[6], float& fx, float& fy, bool& val)
{
    int i, j;
    if (mw == 64) { i = idx >> 6; j = idx & 63; }
    else          { i = idx / mw; j = idx - i * mw; }
    const float dx = s * ((float)j - px);
    const float dy = s * ((float)i - ((float)HEIGHT - 1.0f) * 0.5f);
    const float sx = cx + ca * dx - sa * dy;
    const float sy = cy + sa * dx + ca * dy;
    val = ((float)j < wlim) &&
          (sx >= 0.0f) && (sx <= (float)(Wimg - 1)) &&
          (sy >= 0.0f) && (sy <= (float)(Himg - 1));
    fx = 0.0f; fy = 0.0f;
    if (val) {
        const float x0 = floorf(sx);
        const float y0 = floorf(sy);
        const int x0i = (int)x0;
        const int y0i = (int)y0;
        const int xb  = min(x0i, Wimg - 2);
        const int yb  = min(y0i, Himg - 2);
        fx = (x0i == xb) ? (sx - x0) : 1.0f;   // clamp folded into weight
        fy = (y0i == yb) ? (sy - y0) : 1.0f;
        const float* r0 = img + ((size_t)yb * Wimg + xb) * 3;
        const float* r1 = r0 + (size_t)Wimg * 3;
        __builtin_memcpy(qa, r0, 24);
        __builtin_memcpy(qb, r1, 24);
    }
}

__device__ __forceinline__ void consume_samp(
    int idx, const float qa[6], const float qb[6],
    float fx, float fy, bool val, float* __restrict__ oblk)
{
    float v0 = 0.0f, v1 = 0.0f, v2 = 0.0f;
    if (val) {
        const float w00 = (1.0f - fx) * (1.0f - fy);
        const float w01 = fx * (1.0f - fy);
        const float w10 = (1.0f - fx) * fy;
        const float w11 = fx * fy;
        v0 = qa[0] * w00 + qa[3] * w01 + qb[0] * w10 + qb[3] * w11;
        v1 = qa[1] * w00 + qa[4] * w01 + qb[1] * w10 + qb[4] * w11;
        v2 = qa[2] * w00 + qa[5] * w01 + qb[2] * w10 + qb[5] * w11;
    }
    float* o = oblk + (size_t)idx * 3;
    __builtin_nontemporal_store(v0, o + 0);
    __builtin_nontemporal_store(v1, o + 1);
    __builtin_nontemporal_store(v2, o + 2);
}

__global__ void __launch_bounds__(256)
roi_main_kernel(const float* __restrict__ images,
                const float4* __restrict__ params,
                const int* __restrict__ perm,
                const int* __restrict__ cnt_g,
                float* __restrict__ crops,
                int mw, int Himg, int Wimg, int M)
{
    const int x  = blockIdx.x & (NXCD - 1);     // bucket = XCD (round-robin dispatch)
    const int r  = blockIdx.x >> 3;
    const int nb = (int)gridDim.x >> 3;         // blocks per bucket
    const int t  = threadIdx.x;
    const int cnt   = cnt_g[x];
    const int nsamp = HEIGHT * mw;
    const size_t imgsz = (size_t)Himg * Wimg * 3;

    if (r >= cnt) return;

    // Two boxes per block, fully flattened; all 8 gathers issued before use.
    const int p1 = r + nb;
    const bool h1 = (p1 < cnt);
    const int m0 = perm[x * M + r];
    const int m1 = h1 ? perm[x * M + p1] : m0;   // dup of own box: benign rewrite

    const float4 a0 = params[2 * m0], b0 = params[2 * m0 + 1];
    const float4 a1 = params[2 * m1], b1 = params[2 * m1 + 1];
    const float* img0 = images + (size_t)__float_as_int(b0.w) * imgsz;
    const float* img1 = images + (size_t)__float_as_int(b1.w) * imgsz;

    Gth G0, G1;
    const int i0a = t, i0b = t + 256;            // nsamp==512 fast path
    issue_samp(img0, i0a, mw, Wimg, Himg, a0.x, a0.y, a0.z, a0.w, b0.x, b0.y, b0.z,
               G0.q0, G0.q1, G0.fx0, G0.fy0, G0.v0);
    if (i0b < nsamp)
        issue_samp(img0, i0b, mw, Wimg, Himg, a0.x, a0.y, a0.z, a0.w, b0.x, b0.y, b0.z,
                   G0.q2, G0.q3, G0.fx1, G0.fy1, G0.v1);
    issue_samp(img1, i0a, mw, Wimg, Himg, a1.x, a1.y, a1.z, a1.w, b1.x, b1.y, b1.z,
               G1.q0, G1.q1, G1.fx0, G1.fy0, G1.v0);
    if (i0b < nsamp)
        issue_samp(img1, i0b, mw, Wimg, Himg, a1.x, a1.y, a1.z, a1.w, b1.x, b1.y, b1.z,
                   G1.q2, G1.q3, G1.fx1, G1.fy1, G1.v1);

    float* ob0 = crops + (size_t)m0 * nsamp * 3;
    consume_samp(i0a, G0.q0, G0.q1, G0.fx0, G0.fy0, G0.v0, ob0);
    if (i0b < nsamp) consume_samp(i0b, G0.q2, G0.q3, G0.fx1, G0.fy1, G0.v1, ob0);

    float* ob1 = crops + (size_t)m1 * nsamp * 3;
    consume_samp(i0a, G1.q0, G1.q1, G1.fx0, G1.fy0, G1.v0, ob1);
    if (i0b < nsamp) consume_samp(i0b, G1.q2, G1.q3, G1.fx1, G1.fy1, G1.v1, ob1);

    // Rare tail (bucket larger than 2*nb boxes).
    for (int p = r + 2 * nb; p < cnt; p += nb) {
        const int mm = perm[x * M + p];
        const float4 aa = params[2 * mm], bb = params[2 * mm + 1];
        const float* img = images + (size_t)__float_as_int(bb.w) * imgsz;
        float* ob = crops + (size_t)mm * nsamp * 3;
        Gth Gt;
        issue_samp(img, i0a, mw, Wimg, Himg, aa.x, aa.y, aa.z, aa.w, bb.x, bb.y, bb.z,
                   Gt.q0, Gt.q1, Gt.fx0, Gt.fy0, Gt.v0);
        if (i0b < nsamp)
            issue_samp(img, i0b, mw, Wimg, Himg, aa.x, aa.y, aa.z, aa.w, bb.x, bb.y, bb.z,
                       Gt.q2, Gt.q3, Gt.fx1, Gt.fy1, Gt.v1);
        consume_samp(i0a, Gt.q0, Gt.q1, Gt.fx0, Gt.fy0, Gt.v0, ob);
        if (i0b < nsamp) consume_samp(i0b, Gt.q2, Gt.q3, Gt.fx1, Gt.fy1, Gt.v1, ob);
    }

    // samples beyond 512 per box (only if mw > 64; not hit for this problem)
    for (int idx = t + 512; idx < nsamp; idx += 256) {
        Gth Gt;
        issue_samp(img0, idx, mw, Wimg, Himg, a0.x, a0.y, a0.z, a0.w, b0.x, b0.y, b0.z,
                   Gt.q0, Gt.q1, Gt.fx0, Gt.fy0, Gt.v0);
        consume_samp(idx, Gt.q0, Gt.q1, Gt.fx0, Gt.fy0, Gt.v0, ob0);
        issue_samp(img1, idx, mw, Wimg, Himg, a1.x, a1.y, a1.z, a1.w, b1.x, b1.y, b1.z,
                   Gt.q0, Gt.q1, Gt.fx0, Gt.fy0, Gt.v0);
        consume_samp(idx, Gt.q0, Gt.q1, Gt.fx0, Gt.fy0, Gt.v0, ob1);
    }
}

extern "C" void kernel_launch(void* const* d_in, const int* in_sizes, int n_in,
                              void* d_out, int out_size, void* d_ws, size_t ws_size,
                              hipStream_t stream) {
    const float* images      = (const float*)d_in[0];
    const float* boxes       = (const float*)d_in[2];
    const int*   box_indices = (const int*)d_in[3];

    const int M  = in_sizes[3];                       // 8192 boxes
    const int mw = (out_size - M) / (M * HEIGHT * 3); // max_width (=64)
    const int Himg = 512, Wimg = 512;

    float* crops     = (float*)d_out;
    float* width_out = crops + (size_t)M * HEIGHT * mw * 3;

    // workspace: params (2M float4) | perm (8*M int) | cnt (8 int)
    float4* params = (float4*)d_ws;
    int*    perm   = (int*)((char*)d_ws + (size_t)2 * M * sizeof(float4));
    int*    cnt    = perm + (size_t)NXCD * M;

    hipMemsetAsync(cnt, 0, NXCD * sizeof(int), stream);
    prep_kernel<<<(M + 255) / 256, 256, 0, stream>>>(
        boxes, box_indices, params, perm, cnt, width_out, M, mw);
    roi_main_kernel<<<4096, 256, 0, stream>>>(
        images, params, perm, cnt, crops, mw, Himg, Wimg, M);
}